// Round 1
// baseline (316.235 us; speedup 1.0000x reference)
//
#include <hip/hip_runtime.h>
#include <math.h>

#define D_MODEL 1024
#define N_HEADS 16
#define DKH     64
#define BATCH   2
#define SEQ     2048

typedef unsigned short u16;
typedef __attribute__((ext_vector_type(8))) short short8;
typedef __attribute__((ext_vector_type(4))) float f32x4;

__device__ __forceinline__ u16 f2bf(float f) {
    unsigned u = __float_as_uint(f);
    u += 0x7fffu + ((u >> 16) & 1u);
    return (u16)(u >> 16);
}

// C = X @ W^T + bias.  X:(M,K) fp32 row-major, W:(N,K) fp32 row-major.
// MODE 0: dst = fp32 (M,N) row-major, value = (acc+bias)*scale
// MODE 1: dst = bf16 scattered to (B, H, S, dk):  m=b*SEQ+s, n=h*64+d
template<int MODE>
__global__ __launch_bounds__(256)
void gemm_bias_kernel(const float* __restrict__ X, const float* __restrict__ W,
                      const float* __restrict__ bias, float scale,
                      void* __restrict__ dst, int M, int N, int K)
{
    __shared__ __align__(16) u16 As[64][40];   // 64 rows x 32 cols, +8 pad (80B stride)
    __shared__ __align__(16) u16 Bs[64][40];

    const int tid  = threadIdx.x;
    const int lane = tid & 63;
    const int wid  = tid >> 6;          // 4 waves: 2x2 over the 64x64 tile
    const int wm   = wid >> 1, wn = wid & 1;
    const int lr   = lane & 15, lg = lane >> 4;
    const int mb   = blockIdx.x * 64, nb = blockIdx.y * 64;

    const int srow = tid >> 2;          // staging: 0..63
    const int scol = (tid & 3) << 3;    // 0,8,16,24

    f32x4 acc00 = {0.f,0.f,0.f,0.f};
    f32x4 acc01 = acc00, acc10 = acc00, acc11 = acc00;

    const float* xrow = X + (size_t)(mb + srow) * K + scol;
    const float* wrow = W + (size_t)(nb + srow) * K + scol;

    for (int kt = 0; kt < K; kt += 32) {
        __syncthreads();
        float4 x0 = *(const float4*)(xrow + kt);
        float4 x1 = *(const float4*)(xrow + kt + 4);
        short8 av;
        av[0]=(short)f2bf(x0.x); av[1]=(short)f2bf(x0.y); av[2]=(short)f2bf(x0.z); av[3]=(short)f2bf(x0.w);
        av[4]=(short)f2bf(x1.x); av[5]=(short)f2bf(x1.y); av[6]=(short)f2bf(x1.z); av[7]=(short)f2bf(x1.w);
        *(short8*)&As[srow][scol] = av;
        float4 w0 = *(const float4*)(wrow + kt);
        float4 w1 = *(const float4*)(wrow + kt + 4);
        short8 bvv;
        bvv[0]=(short)f2bf(w0.x); bvv[1]=(short)f2bf(w0.y); bvv[2]=(short)f2bf(w0.z); bvv[3]=(short)f2bf(w0.w);
        bvv[4]=(short)f2bf(w1.x); bvv[5]=(short)f2bf(w1.y); bvv[6]=(short)f2bf(w1.z); bvv[7]=(short)f2bf(w1.w);
        *(short8*)&Bs[srow][scol] = bvv;
        __syncthreads();

        short8 a0 = *(short8*)&As[wm*32 +  0 + lr][lg*8];
        short8 a1 = *(short8*)&As[wm*32 + 16 + lr][lg*8];
        short8 b0 = *(short8*)&Bs[wn*32 +  0 + lr][lg*8];
        short8 b1 = *(short8*)&Bs[wn*32 + 16 + lr][lg*8];
        acc00 = __builtin_amdgcn_mfma_f32_16x16x32_bf16(a0, b0, acc00, 0, 0, 0);
        acc01 = __builtin_amdgcn_mfma_f32_16x16x32_bf16(a0, b1, acc01, 0, 0, 0);
        acc10 = __builtin_amdgcn_mfma_f32_16x16x32_bf16(a1, b0, acc10, 0, 0, 0);
        acc11 = __builtin_amdgcn_mfma_f32_16x16x32_bf16(a1, b1, acc11, 0, 0, 0);
    }

    // epilogue
    #pragma unroll
    for (int i = 0; i < 2; ++i) {
        #pragma unroll
        for (int j = 0; j < 2; ++j) {
            f32x4 a = (i==0) ? (j==0 ? acc00 : acc01) : (j==0 ? acc10 : acc11);
            const int mbase = mb + wm*32 + i*16 + lg*4;
            const int n     = nb + wn*32 + j*16 + lr;
            const float bn  = bias[n];
            #pragma unroll
            for (int r = 0; r < 4; ++r) {
                const int m = mbase + r;
                const float val = (a[r] + bn) * scale;
                if (MODE == 0) {
                    ((float*)dst)[(size_t)m * N + n] = val;
                } else {
                    const int b = m >> 11, s = m & (SEQ - 1);
                    const int h = n >> 6,  d = n & 63;
                    ((u16*)dst)[(((size_t)(b*N_HEADS + h))*SEQ + s)*DKH + d] = f2bf(val);
                }
            }
        }
    }
}

// Flash attention, causal. Qh/Kh/Vh: (B*H, S, 64) bf16 (Q pre-scaled by 1/8).
// attn out: (B, S, D_MODEL) fp32.
__global__ __launch_bounds__(256)
void flash_attn_kernel(const u16* __restrict__ Qh, const u16* __restrict__ Kh,
                       const u16* __restrict__ Vh, float* __restrict__ attn)
{
    __shared__ __align__(16) u16 P[4][16][40];   // per-wave P tile (16 q x 32 kv)

    const int tid  = threadIdx.x;
    const int lane = tid & 63;
    const int wid  = tid >> 6;
    const int lr   = lane & 15, lg = lane >> 4;
    const int qt   = blockIdx.x;            // q tile of 64
    const int bh   = blockIdx.y;            // b*H + h
    const int qbw  = qt*64 + wid*16;        // wave's first q row
    const size_t base = (size_t)bh * SEQ * DKH;

    // Q fragments (16 rows x 64 d) held in registers
    short8 aq0 = *(const short8*)&Qh[base + (size_t)(qbw + lr)*DKH +  0 + lg*8];
    short8 aq1 = *(const short8*)&Qh[base + (size_t)(qbw + lr)*DKH + 32 + lg*8];

    f32x4 o[4];
    float m_run[4], l_run[4];
    #pragma unroll
    for (int r = 0; r < 4; ++r) { m_run[r] = -INFINITY; l_run[r] = 0.f; }
    #pragma unroll
    for (int db = 0; db < 4; ++db) { f32x4 z = {0.f,0.f,0.f,0.f}; o[db] = z; }

    const int nc = (qbw >> 5) + 1;          // kv tiles of 32 needed (causal)
    for (int c = 0; c < nc; ++c) {
        const int kvb = c * 32;

        // S = Q K^T  (16 q x 32 kv), two 16-col blocks
        f32x4 s[2];
        #pragma unroll
        for (int cb = 0; cb < 2; ++cb) {
            f32x4 z = {0.f,0.f,0.f,0.f};
            const u16* kp = &Kh[base + (size_t)(kvb + cb*16 + lr)*DKH + lg*8];
            short8 k0 = *(const short8*)(kp);
            short8 k1 = *(const short8*)(kp + 32);
            z = __builtin_amdgcn_mfma_f32_16x16x32_bf16(aq0, k0, z, 0, 0, 0);
            z = __builtin_amdgcn_mfma_f32_16x16x32_bf16(aq1, k1, z, 0, 0, 0);
            s[cb] = z;
        }

        // causal mask (only relevant for the trailing tile(s))
        if (kvb + 31 > qbw) {
            #pragma unroll
            for (int cb = 0; cb < 2; ++cb)
                #pragma unroll
                for (int r = 0; r < 4; ++r)
                    if (kvb + cb*16 + lr > qbw + lg*4 + r) s[cb][r] = -INFINITY;
        }

        // online softmax
        float alpha[4];
        #pragma unroll
        for (int r = 0; r < 4; ++r) {
            float tm = fmaxf(s[0][r], s[1][r]);
            #pragma unroll
            for (int off = 1; off < 16; off <<= 1) tm = fmaxf(tm, __shfl_xor(tm, off));
            const float mnew = fmaxf(m_run[r], tm);
            alpha[r] = expf(m_run[r] - mnew);     // m_run=-inf -> 0
            const float p0 = expf(s[0][r] - mnew);
            const float p1 = expf(s[1][r] - mnew);
            P[wid][lg*4 + r][lr]      = f2bf(p0);
            P[wid][lg*4 + r][16 + lr] = f2bf(p1);
            float ts = p0 + p1;
            #pragma unroll
            for (int off = 1; off < 16; off <<= 1) ts += __shfl_xor(ts, off);
            l_run[r] = l_run[r]*alpha[r] + ts;
            m_run[r] = mnew;
        }
        #pragma unroll
        for (int db = 0; db < 4; ++db)
            #pragma unroll
            for (int r = 0; r < 4; ++r) o[db][r] *= alpha[r];

        // O += P @ V
        short8 ap = *(short8*)&P[wid][lr][lg*8];
        #pragma unroll
        for (int db = 0; db < 4; ++db) {
            short8 bv;
            #pragma unroll
            for (int j = 0; j < 8; ++j)
                bv[j] = (short)Vh[base + (size_t)(kvb + lg*8 + j)*DKH + db*16 + lr];
            o[db] = __builtin_amdgcn_mfma_f32_16x16x32_bf16(ap, bv, o[db], 0, 0, 0);
        }
    }

    const int b = bh >> 4, h = bh & 15;
    #pragma unroll
    for (int db = 0; db < 4; ++db) {
        #pragma unroll
        for (int r = 0; r < 4; ++r) {
            const int s_ = qbw + lg*4 + r;
            attn[((size_t)(b*SEQ + s_))*D_MODEL + h*64 + db*16 + lr] = o[db][r] / l_run[r];
        }
    }
}

extern "C" void kernel_launch(void* const* d_in, const int* in_sizes, int n_in,
                              void* d_out, int out_size, void* d_ws, size_t ws_size,
                              hipStream_t stream)
{
    const float* q   = (const float*)d_in[0];
    const float* k   = (const float*)d_in[1];
    const float* v   = (const float*)d_in[2];
    // d_in[3] = mask (causal tril) — computed analytically in-kernel
    const float* w_q = (const float*)d_in[4];
    const float* b_q = (const float*)d_in[5];
    const float* w_k = (const float*)d_in[6];
    const float* b_k = (const float*)d_in[7];
    const float* w_v = (const float*)d_in[8];
    const float* b_v = (const float*)d_in[9];
    const float* w_o = (const float*)d_in[10];
    const float* b_o = (const float*)d_in[11];

    char* ws = (char*)d_ws;
    u16*   Qh  = (u16*)(ws);                               //  8 MiB bf16 (B,H,S,dk)
    u16*   Kh  = (u16*)(ws + (size_t)8*1024*1024);         //  8 MiB
    u16*   Vh  = (u16*)(ws + (size_t)16*1024*1024);        //  8 MiB
    float* att = (float*)(ws + (size_t)24*1024*1024);      // 16 MiB fp32 (B,S,D)

    const int M = BATCH * SEQ, N = D_MODEL, K = D_MODEL;
    dim3 gg(M/64, N/64);
    // Q projection carries the 1/sqrt(dk)=0.125 score scale (exact in bf16)
    gemm_bias_kernel<1><<<gg, 256, 0, stream>>>(q, w_q, b_q, 0.125f, Qh, M, N, K);
    gemm_bias_kernel<1><<<gg, 256, 0, stream>>>(k, w_k, b_k, 1.0f,   Kh, M, N, K);
    gemm_bias_kernel<1><<<gg, 256, 0, stream>>>(v, w_v, b_v, 1.0f,   Vh, M, N, K);
    flash_attn_kernel<<<dim3(SEQ/64, BATCH*N_HEADS), 256, 0, stream>>>(Qh, Kh, Vh, att);
    gemm_bias_kernel<0><<<gg, 256, 0, stream>>>(att, w_o, b_o, 1.0f, d_out, M, N, K);
}